// Round 3
// baseline (163.208 us; speedup 1.0000x reference)
//
#include <hip/hip_runtime.h>

// Problem constants (fixed-shape per reference)
#define B_SIZE 16384
#define D_DIM  1024
#define T_DIM  128
#define VLn    12        // V*L
#define ROWS   32        // rows per block (2 x 16-row MFMA tiles, shared B-frags)
#define KPW    256       // K-range per wave (D_DIM / 4 waves)
#define NCHUNK 8         // KPW / 32
#define STRIDE 132       // LDS row stride (floats): 2-way bank pattern = free

typedef __attribute__((ext_vector_type(8))) short  short8;  // 8 bf16
typedef __attribute__((ext_vector_type(4))) float  f32x4;   // MFMA acc

__device__ __forceinline__ unsigned short f2bf(float f) {
    union { float f; unsigned int u; } c; c.f = f;
    unsigned int u = c.u;
    return (unsigned short)((u + 0x7FFFu + ((u >> 16) & 1u)) >> 16);
}

__device__ __forceinline__ short8 pack_bf16(float4 a, float4 b) {
    short8 r;
    r[0] = (short)f2bf(a.x); r[1] = (short)f2bf(a.y);
    r[2] = (short)f2bf(a.z); r[3] = (short)f2bf(a.w);
    r[4] = (short)f2bf(b.x); r[5] = (short)f2bf(b.y);
    r[6] = (short)f2bf(b.z); r[7] = (short)f2bf(b.w);
    return r;
}

// One-time W fp32 -> bf16 into workspace (must run every launch: ws re-poisoned).
__global__ __launch_bounds__(256)
void conv_w_kernel(const float* __restrict__ W, unsigned short* __restrict__ Wb) {
    const int i = (blockIdx.x * 256 + threadIdx.x) * 4;
    const float4 v = *(const float4*)(W + i);
    ushort4 h; h.x = f2bf(v.x); h.y = f2bf(v.y); h.z = f2bf(v.z); h.w = f2bf(v.w);
    *(ushort4*)(Wb + i) = h;
}

// 512 blocks x 256 threads. Block owns 32 rows; wave w covers K [w*256,(w+1)*256)
// for all 32 rows x 128 cols (16 MFMAs per chunk on 8 shared B-frags).
// Partials combined via LDS atomicAdd into bias-initialized logit buffer.
__global__ __launch_bounds__(256, 2)
void qloss_kernel(const float* __restrict__ emb,
                  const unsigned short* __restrict__ Wb,
                  const float* __restrict__ bias,
                  const int*   __restrict__ didx,
                  const int*   __restrict__ dmsk,
                  float*       __restrict__ out)
{
    __shared__ float sL[ROWS * STRIDE + 8];   // 16928 B
    const int t    = threadIdx.x;
    const int w    = t >> 6;
    const int lane = t & 63;
    const int m15  = lane & 15;
    const int quad = lane >> 4;
    const int r0   = blockIdx.x * ROWS;

    // Init logit buffer with bias (cols >= 128 never read).
#pragma unroll
    for (int i = t; i < ROWS * T_DIM; i += 256) {
        const int row = i >> 7, col = i & 127;
        sL[row * STRIDE + col] = bias[col];
    }
    if (t < 8) sL[ROWS * STRIDE + t] = 0.f;
    __syncthreads();

    f32x4 acc[2][8];
#pragma unroll
    for (int mt = 0; mt < 2; ++mt)
#pragma unroll
        for (int ct = 0; ct < 8; ++ct) acc[mt][ct] = (f32x4){0.f, 0.f, 0.f, 0.f};

    // Per-lane fragment pointers. A: [m=m15(+16)][k=quad*8+j]; B: [n=ct*16+m15][k].
    const float*          aptr0 = emb + (size_t)(r0 + m15) * D_DIM + w * KPW + quad * 8;
    const float*          aptr1 = aptr0 + 16 * D_DIM;
    const unsigned short* bptr  = Wb  + (size_t)m15 * D_DIM + w * KPW + quad * 8;

    // Manual 1-deep register prefetch: issue chunk k+1 loads before chunk k MFMAs.
    float4 x0 = *(const float4*)(aptr0);
    float4 x1 = *(const float4*)(aptr0 + 4);
    float4 y0 = *(const float4*)(aptr1);
    float4 y1 = *(const float4*)(aptr1 + 4);
    short8 bf[8];
#pragma unroll
    for (int ct = 0; ct < 8; ++ct)
        bf[ct] = *(const short8*)(bptr + (size_t)ct * 16 * D_DIM);

#pragma unroll
    for (int kc = 0; kc < NCHUNK; ++kc) {
        const float4 cx0 = x0, cx1 = x1, cy0 = y0, cy1 = y1;
        short8 cbf[8];
#pragma unroll
        for (int ct = 0; ct < 8; ++ct) cbf[ct] = bf[ct];
        if (kc + 1 < NCHUNK) {
            const int ko = (kc + 1) * 32;
            x0 = *(const float4*)(aptr0 + ko);
            x1 = *(const float4*)(aptr0 + ko + 4);
            y0 = *(const float4*)(aptr1 + ko);
            y1 = *(const float4*)(aptr1 + ko + 4);
#pragma unroll
            for (int ct = 0; ct < 8; ++ct)
                bf[ct] = *(const short8*)(bptr + (size_t)ct * 16 * D_DIM + ko);
        }
        const short8 a0 = pack_bf16(cx0, cx1);
        const short8 a1 = pack_bf16(cy0, cy1);
#pragma unroll
        for (int ct = 0; ct < 8; ++ct) {
            acc[0][ct] = __builtin_amdgcn_mfma_f32_16x16x32_bf16(a0, cbf[ct], acc[0][ct], 0, 0, 0);
            acc[1][ct] = __builtin_amdgcn_mfma_f32_16x16x32_bf16(a1, cbf[ct], acc[1][ct], 0, 0, 0);
        }
    }

    // Accumulate partials. C/D: col = ct*16+m15, row = mt*16 + quad*4 + i.
    // Bank pattern per op: (quad*16 + m15) % 32 -> 2-way (free).
#pragma unroll
    for (int mt = 0; mt < 2; ++mt)
#pragma unroll
        for (int ct = 0; ct < 8; ++ct)
#pragma unroll
            for (int i = 0; i < 4; ++i)
                atomicAdd(&sL[(mt * 16 + quad * 4 + i) * STRIDE + ct * 16 + m15],
                          acc[mt][ct][i]);
    __syncthreads();

    // Softmax: 8 threads/row, 16 cols each.
    {
        const int row = t >> 3, s = t & 7;
        float* base = &sL[row * STRIDE + s * 16];
        float v[16];
#pragma unroll
        for (int j = 0; j < 4; ++j) *(float4*)&v[j * 4] = *(const float4*)(base + j * 4);
        float m = -1e30f;
#pragma unroll
        for (int j = 0; j < 16; ++j) m = fmaxf(m, v[j]);
#pragma unroll
        for (int off = 1; off < 8; off <<= 1) m = fmaxf(m, __shfl_xor(m, off));
        float ssum = 0.f;
#pragma unroll
        for (int j = 0; j < 16; ++j) { v[j] = __expf(v[j] - m); ssum += v[j]; }
#pragma unroll
        for (int off = 1; off < 8; off <<= 1) ssum += __shfl_xor(ssum, off);
        const float inv = 1.0f / ssum;
#pragma unroll
        for (int j = 0; j < 16; ++j) v[j] *= inv;
#pragma unroll
        for (int j = 0; j < 4; ++j) *(float4*)(base + j * 4) = *(const float4*)&v[j * 4];
    }
    __syncthreads();

    // Gather: 384 (row, j) entries; didx flat index = r0*12 + i.
    float p = 0.f;
#pragma unroll
    for (int i = t; i < ROWS * VLn; i += 256) {
        const int gi  = r0 * VLn + i;
        const int row = i / VLn;
        const int idx = didx[gi];
        const int mk  = dmsk[gi];
        p += mk ? sL[row * STRIDE + idx] : 0.f;
    }
#pragma unroll
    for (int off = 1; off < 64; off <<= 1) p += __shfl_xor(p, off);
    if (lane == 0) sL[ROWS * STRIDE + w] = p;
    __syncthreads();
    if (t == 0) {
        const float tot = sL[ROWS * STRIDE] + sL[ROWS * STRIDE + 1]
                        + sL[ROWS * STRIDE + 2] + sL[ROWS * STRIDE + 3];
        atomicAdd(out, tot * (1.0f / 65536.0f));   // / (V * B)
    }
}

extern "C" void kernel_launch(void* const* d_in, const int* in_sizes, int n_in,
                              void* d_out, int out_size, void* d_ws, size_t ws_size,
                              hipStream_t stream) {
    const float* emb  = (const float*)d_in[0];
    const float* W    = (const float*)d_in[1];
    const float* bias = (const float*)d_in[2];
    const int*   didx = (const int*)d_in[3];
    const int*   dmsk = (const int*)d_in[4];
    float* out = (float*)d_out;
    unsigned short* Wb = (unsigned short*)d_ws;   // 256 KB bf16 W

    hipMemsetAsync(out, 0, sizeof(float), stream);
    conv_w_kernel<<<(T_DIM * D_DIM) / (256 * 4), 256, 0, stream>>>(W, Wb);
    qloss_kernel<<<B_SIZE / ROWS, 256, 0, stream>>>(emb, Wb, bias, didx, dmsk, out);
}

// Round 5
// 116.505 us; speedup vs baseline: 1.4009x; 1.4009x over previous
//
#include <hip/hip_runtime.h>

// Problem constants
#define B_SIZE 16384
#define D_DIM  1024
#define T_DIM  128
#define VLn    12
#define BM     32          // rows per block
#define BK     64          // K per chunk
#define NCHUNK (D_DIM / BK)   // 16
#define GRID   (B_SIZE / BM)  // 512
#define SL_STRIDE 132

typedef _Float16 half8  __attribute__((ext_vector_type(8)));
typedef __fp16   fp16x2 __attribute__((ext_vector_type(2)));
typedef float    f32x4  __attribute__((ext_vector_type(4)));

union Pack16 { fp16x2 h[4]; uint4 u; };

__device__ __forceinline__ uint4 pack8(float4 v0, float4 v1) {
    Pack16 un;
    un.h[0] = __builtin_amdgcn_cvt_pkrtz(v0.x, v0.y);
    un.h[1] = __builtin_amdgcn_cvt_pkrtz(v0.z, v0.w);
    un.h[2] = __builtin_amdgcn_cvt_pkrtz(v1.x, v1.y);
    un.h[3] = __builtin_amdgcn_cvt_pkrtz(v1.z, v1.w);
    return un.u;
}

// W fp32 [128][1024] -> f16, swizzled into MFMA B-fragment order:
// unit j (16 B = 8 f16): kc=j>>10, g=(j&1023)>>6 (g = ks*8+CT), lane=j&63;
// holds W[n = CT*16 + (lane&15)][k = kc*64 + ks*32 + (lane>>4)*8 .. +8].
__global__ __launch_bounds__(256)
void conv_w(const float* __restrict__ W, uint4* __restrict__ Wf) {
    const int j    = blockIdx.x * 256 + threadIdx.x;   // 0..16383
    const int kc   = j >> 10;
    const int r    = j & 1023;
    const int g    = r >> 6;
    const int lane = r & 63;
    const int ks = g >> 3, CT = g & 7;
    const int n = CT * 16 + (lane & 15);
    const int k = kc * 64 + ks * 32 + ((lane >> 4) << 3);
    const float* src = W + (size_t)n * D_DIM + k;
    const float4 v0 = *(const float4*)src;
    const float4 v1 = *(const float4*)(src + 4);
    Wf[j] = pack8(v0, v1);
}

// 512 blocks x 256 threads (4 waves). Block = 32 rows x 128 cols x full K.
// Wave w owns n-quarter [w*32, w*32+32) (2 col-tiles), all 32 rows.
// LDS: double-buffered A (f16, frag-major, 4 KB) + W (f16, frag-major, 16 KB).
__global__ __launch_bounds__(256, 2)
void qloss_kernel(const float* __restrict__ emb,
                  const uint4* __restrict__ Wf,
                  const float* __restrict__ bias,
                  const int*   __restrict__ didx,
                  const int*   __restrict__ dmsk,
                  float*       __restrict__ part)
{
    __shared__ __align__(16) unsigned char smem[40960 + 32];
    // buffers: sA0 @0 (4 KB), sA1 @4096, sW0 @8192 (16 KB), sW1 @24576
    float* sL   = (float*)smem;                 // epilogue alias [32][132]
    float* sRed = (float*)(smem + 40960);

    const int t    = threadIdx.x;
    const int w    = t >> 6;
    const int lane = t & 63;
    const int m15  = lane & 15;
    const int quad = lane >> 4;
    const int r0   = blockIdx.x * BM;

    // A staging map: thread t stages unit t of the A tile each chunk.
    // unit t: g=t>>6 (mt=g>>1, ks=g&1), sl=t&63;
    // row = mt*16 + (sl&15), k-offset = ks*32 + (sl>>4)*8.
    const int sg   = t >> 6, sl = t & 63;
    const int srow = (sg >> 1) * 16 + (sl & 15);
    const int skk  = (sg & 1) * 32 + ((sl >> 4) << 3);
    const float* aBase = emb + (size_t)(r0 + srow) * D_DIM + skk;

    f32x4 acc[2][2];
#pragma unroll
    for (int mt = 0; mt < 2; ++mt)
#pragma unroll
        for (int ct = 0; ct < 2; ++ct) acc[mt][ct] = (f32x4){0.f, 0.f, 0.f, 0.f};

    // ---- prologue: stage chunk 0 into buffer 0 ----
    {
        const float4 v0 = *(const float4*)(aBase);
        const float4 v1 = *(const float4*)(aBase + 4);
        *(uint4*)(smem + t * 16) = pack8(v0, v1);           // sA0
#pragma unroll
        for (int p = 0; p < 4; ++p) {
            const int u = t + p * 256;
            *(uint4*)(smem + 8192 + u * 16) = Wf[u];        // sW0, kc=0
        }
    }
    __syncthreads();

    for (int kc = 0; kc < NCHUNK; ++kc) {
        const int cur = kc & 1;
        unsigned char* sAc = smem + cur * 4096;
        unsigned char* sWc = smem + 8192 + cur * 16384;
        unsigned char* sAn = smem + (cur ^ 1) * 4096;
        unsigned char* sWn = smem + 8192 + (cur ^ 1) * 16384;

        // prefetch next chunk into registers (flies during MFMAs below)
        float4 v0, v1; uint4 wv[4];
        if (kc + 1 < NCHUNK) {
            v0 = *(const float4*)(aBase + (kc + 1) * 64);
            v1 = *(const float4*)(aBase + (kc + 1) * 64 + 4);
#pragma unroll
            for (int p = 0; p < 4; ++p)
                wv[p] = Wf[(size_t)(kc + 1) * 1024 + t + p * 256];
        }

        // compute: 2 K=32 steps, 4 MFMAs each (2 m-tiles x 2 n-tiles)
#pragma unroll
        for (int ks = 0; ks < 2; ++ks) {
            const half8 a0 = *(const half8*)(sAc + ((0 * 2 + ks) * 64 + lane) * 16);
            const half8 a1 = *(const half8*)(sAc + ((1 * 2 + ks) * 64 + lane) * 16);
            const half8 b0 = *(const half8*)(sWc + ((ks * 8 + w * 2 + 0) * 64 + lane) * 16);
            const half8 b1 = *(const half8*)(sWc + ((ks * 8 + w * 2 + 1) * 64 + lane) * 16);
            acc[0][0] = __builtin_amdgcn_mfma_f32_16x16x32_f16(a0, b0, acc[0][0], 0, 0, 0);
            acc[0][1] = __builtin_amdgcn_mfma_f32_16x16x32_f16(a0, b1, acc[0][1], 0, 0, 0);
            acc[1][0] = __builtin_amdgcn_mfma_f32_16x16x32_f16(a1, b0, acc[1][0], 0, 0, 0);
            acc[1][1] = __builtin_amdgcn_mfma_f32_16x16x32_f16(a1, b1, acc[1][1], 0, 0, 0);
        }

        // store staged next chunk
        if (kc + 1 < NCHUNK) {
            *(uint4*)(sAn + t * 16) = pack8(v0, v1);
#pragma unroll
            for (int p = 0; p < 4; ++p) {
                const int u = t + p * 256;
                *(uint4*)(sWn + u * 16) = wv[p];
            }
        }
        __syncthreads();
    }

    // ---- epilogue: logits -> sL (aliases staging; all reads done) ----
    const int CT0 = w * 2;
    const float b0v = bias[CT0 * 16 + m15];
    const float b1v = bias[(CT0 + 1) * 16 + m15];
#pragma unroll
    for (int mt = 0; mt < 2; ++mt)
#pragma unroll
        for (int i = 0; i < 4; ++i) {
            const int row = mt * 16 + quad * 4 + i;
            sL[row * SL_STRIDE + CT0 * 16 + m15]       = acc[mt][0][i] + b0v;
            sL[row * SL_STRIDE + (CT0 + 1) * 16 + m15] = acc[mt][1][i] + b1v;
        }
    __syncthreads();

    // softmax: 8 threads/row, 16 cols each (xor 1,2,4 stays in the 8-group)
    {
        const int row = t >> 3, s = t & 7;
        float* base = &sL[row * SL_STRIDE + s * 16];
        float v[16];
#pragma unroll
        for (int j = 0; j < 4; ++j) *(float4*)&v[j * 4] = *(const float4*)(base + j * 4);
        float m = -1e30f;
#pragma unroll
        for (int j = 0; j < 16; ++j) m = fmaxf(m, v[j]);
#pragma unroll
        for (int off = 1; off < 8; off <<= 1) m = fmaxf(m, __shfl_xor(m, off));
        float ssum = 0.f;
#pragma unroll
        for (int j = 0; j < 16; ++j) { v[j] = __expf(v[j] - m); ssum += v[j]; }
#pragma unroll
        for (int off = 1; off < 8; off <<= 1) ssum += __shfl_xor(ssum, off);
        const float inv = 1.0f / ssum;
#pragma unroll
        for (int j = 0; j < 16; ++j) v[j] *= inv;
#pragma unroll
        for (int j = 0; j < 4; ++j) *(float4*)(base + j * 4) = *(const float4*)&v[j * 4];
    }
    __syncthreads();

    // gather: 384 (row, j) entries
    float p = 0.f;
#pragma unroll
    for (int i = t; i < BM * VLn; i += 256) {
        const int gi  = r0 * VLn + i;
        const int row = i / VLn;
        const int idx = didx[gi];
        const int mk  = dmsk[gi];
        p += mk ? sL[row * SL_STRIDE + idx] : 0.f;
    }
#pragma unroll
    for (int off = 1; off < 64; off <<= 1) p += __shfl_xor(p, off);
    if (lane == 0) sRed[w] = p;
    __syncthreads();
    if (t == 0) part[blockIdx.x] = sRed[0] + sRed[1] + sRed[2] + sRed[3];
}

// Final reduce: 512 partials -> scalar (avoids 512-way same-address atomics)
__global__ __launch_bounds__(256)
void reduce_k(const float* __restrict__ part, float* __restrict__ out) {
    __shared__ float s[4];
    const int t = threadIdx.x;
    float p = part[t] + part[t + 256];
#pragma unroll
    for (int off = 1; off < 64; off <<= 1) p += __shfl_xor(p, off);
    if ((t & 63) == 0) s[t >> 6] = p;
    __syncthreads();
    if (t == 0) out[0] = (s[0] + s[1] + s[2] + s[3]) * (1.0f / 65536.0f); // /(V*B)
}

extern "C" void kernel_launch(void* const* d_in, const int* in_sizes, int n_in,
                              void* d_out, int out_size, void* d_ws, size_t ws_size,
                              hipStream_t stream) {
    const float* emb  = (const float*)d_in[0];
    const float* W    = (const float*)d_in[1];
    const float* bias = (const float*)d_in[2];
    const int*   didx = (const int*)d_in[3];
    const int*   dmsk = (const int*)d_in[4];
    float* out = (float*)d_out;

    uint4* Wf   = (uint4*)d_ws;                        // 256 KB swizzled f16 W
    float* part = (float*)((char*)d_ws + 262144);      // 512 block partials

    conv_w<<<64, 256, 0, stream>>>(W, Wf);
    qloss_kernel<<<GRID, 256, 0, stream>>>(emb, Wf, bias, didx, dmsk, part);
    reduce_k<<<1, 256, 0, stream>>>(part, out);
}

// Round 6
// 115.526 us; speedup vs baseline: 1.4127x; 1.0085x over previous
//
#include <hip/hip_runtime.h>

// Problem constants
#define B_SIZE 16384
#define D_DIM  1024
#define T_DIM  128
#define VLn    12
#define BM     32             // rows per block
#define BK     64             // K per chunk
#define NCHUNK (D_DIM / BK)   // 16
#define GRID   (B_SIZE / BM)  // 512
#define SL_STRIDE 132

typedef _Float16 half8  __attribute__((ext_vector_type(8)));
typedef __fp16   fp16x2 __attribute__((ext_vector_type(2)));
typedef float    f32x4  __attribute__((ext_vector_type(4)));

union Pack16 { fp16x2 h[4]; uint4 u; };
union BReg   { uint4 u; half8 h; };

__device__ __forceinline__ uint4 pack8(float4 v0, float4 v1) {
    Pack16 un;
    un.h[0] = __builtin_amdgcn_cvt_pkrtz(v0.x, v0.y);
    un.h[1] = __builtin_amdgcn_cvt_pkrtz(v0.z, v0.w);
    un.h[2] = __builtin_amdgcn_cvt_pkrtz(v1.x, v1.y);
    un.h[3] = __builtin_amdgcn_cvt_pkrtz(v1.z, v1.w);
    return un.u;
}

// W fp32 [128][1024] -> f16, swizzled into MFMA B-fragment order:
// unit j (16 B = 8 f16): kc=j>>10, g=(j&1023)>>6 (g = ks*8+CT), lane=j&63;
// holds W[n = CT*16 + (lane&15)][k = kc*64 + ks*32 + (lane>>4)*8 .. +8].
__global__ __launch_bounds__(256)
void conv_w(const float* __restrict__ W, uint4* __restrict__ Wf) {
    const int j    = blockIdx.x * 256 + threadIdx.x;   // 0..16383
    const int kc   = j >> 10;
    const int r    = j & 1023;
    const int g    = r >> 6;
    const int lane = r & 63;
    const int ks = g >> 3, CT = g & 7;
    const int n = CT * 16 + (lane & 15);
    const int k = kc * 64 + ks * 32 + ((lane >> 4) << 3);
    const float* src = W + (size_t)n * D_DIM + k;
    const float4 v0 = *(const float4*)src;
    const float4 v1 = *(const float4*)(src + 4);
    Wf[j] = pack8(v0, v1);
}

// 512 blocks x 256 threads (4 waves). Block = 32 rows x 128 cols x full K.
// Wave w owns cols [w*32, w*32+32) (col-tiles 2w, 2w+1).
// A: double-buffered LDS (4 KB/buf, frag-major f16). W: NO LDS — direct
// global B-frag loads from pre-swizzled Wf, 2 chunks ahead in registers.
__global__ __launch_bounds__(256, 4)
void qloss_kernel(const float* __restrict__ emb,
                  const uint4* __restrict__ Wf,
                  const float* __restrict__ bias,
                  const int*   __restrict__ didx,
                  const int*   __restrict__ dmsk,
                  float*       __restrict__ part)
{
    __shared__ __align__(16) unsigned char smem[16928];
    // staging: sA0 @0 (4 KB), sA1 @4096. epilogue alias: sL [32][132] f32 + sRed
    float* sL   = (float*)smem;
    float* sRed = (float*)(smem + 16896);

    const int t    = threadIdx.x;
    const int w    = t >> 6;
    const int lane = t & 63;
    const int m15  = lane & 15;
    const int quad = lane >> 4;
    const int r0   = blockIdx.x * BM;

    // A staging map (verified R5): thread t stages unit t each chunk.
    // unit t: g=t>>6 (mt=g>>1, ks=g&1), sl=t&63;
    // row = mt*16 + (sl&15), k-offset = ks*32 + (sl>>4)*8.
    const int sg   = t >> 6, sl = t & 63;
    const int srow = (sg >> 1) * 16 + (sl & 15);
    const int skk  = (sg & 1) * 32 + ((sl >> 4) << 3);
    const float* aBase = emb + (size_t)(r0 + srow) * D_DIM + skk;

    // B-frag base: wave w, frag (ks, j): Wf[kc*1024 + (ks*8 + 2w+j)*64 + lane]
    const uint4* wBase = Wf + (size_t)(2 * w) * 64 + lane;

    f32x4 acc[2][2];
#pragma unroll
    for (int mt = 0; mt < 2; ++mt)
#pragma unroll
        for (int ct = 0; ct < 2; ++ct) acc[mt][ct] = (f32x4){0.f, 0.f, 0.f, 0.f};

    // ---- prologue: stage A chunk 0; B-frags for chunks 0 and 1 ----
    BReg bcur[4], bnx1[4], bnx2[4];
    {
        const float4 v0 = *(const float4*)(aBase);
        const float4 v1 = *(const float4*)(aBase + 4);
        *(uint4*)(smem + t * 16) = pack8(v0, v1);
#pragma unroll
        for (int ks = 0; ks < 2; ++ks)
#pragma unroll
            for (int j = 0; j < 2; ++j) {
                bcur[ks * 2 + j].u = wBase[(size_t)(ks * 8 + j) * 64];
                bnx1[ks * 2 + j].u = wBase[(size_t)1 * 1024 + (ks * 8 + j) * 64];
            }
    }
    __syncthreads();

#pragma unroll
    for (int kc = 0; kc < NCHUNK; ++kc) {
        unsigned char* sAc = smem + (kc & 1) * 4096;
        unsigned char* sAn = smem + ((kc & 1) ^ 1) * 4096;

        // issue A global for kc+1 first (consumed by ds_write below),
        // then B global for kc+2 (stays in flight longer)
        float4 va0, va1;
        if (kc + 1 < NCHUNK) {
            va0 = *(const float4*)(aBase + (kc + 1) * 64);
            va1 = *(const float4*)(aBase + (kc + 1) * 64 + 4);
        }
        if (kc + 2 < NCHUNK) {
#pragma unroll
            for (int ks = 0; ks < 2; ++ks)
#pragma unroll
                for (int j = 0; j < 2; ++j)
                    bnx2[ks * 2 + j].u =
                        wBase[(size_t)(kc + 2) * 1024 + (ks * 8 + j) * 64];
        }

        // compute chunk kc: A frags from LDS, B frags from registers
#pragma unroll
        for (int ks = 0; ks < 2; ++ks) {
            const half8 a0 = *(const half8*)(sAc + ((0 * 2 + ks) * 64 + lane) * 16);
            const half8 a1 = *(const half8*)(sAc + ((1 * 2 + ks) * 64 + lane) * 16);
            acc[0][0] = __builtin_amdgcn_mfma_f32_16x16x32_f16(a0, bcur[ks * 2 + 0].h, acc[0][0], 0, 0, 0);
            acc[0][1] = __builtin_amdgcn_mfma_f32_16x16x32_f16(a0, bcur[ks * 2 + 1].h, acc[0][1], 0, 0, 0);
            acc[1][0] = __builtin_amdgcn_mfma_f32_16x16x32_f16(a1, bcur[ks * 2 + 0].h, acc[1][0], 0, 0, 0);
            acc[1][1] = __builtin_amdgcn_mfma_f32_16x16x32_f16(a1, bcur[ks * 2 + 1].h, acc[1][1], 0, 0, 0);
        }

        // stage A kc+1; rotate B pipeline
        if (kc + 1 < NCHUNK)
            *(uint4*)(sAn + t * 16) = pack8(va0, va1);
#pragma unroll
        for (int q = 0; q < 4; ++q) { bcur[q] = bnx1[q]; bnx1[q] = bnx2[q]; }
        __syncthreads();
    }

    // ---- epilogue: logits -> sL ----
    const int CT0 = w * 2;
    const float b0v = bias[CT0 * 16 + m15];
    const float b1v = bias[(CT0 + 1) * 16 + m15];
#pragma unroll
    for (int mt = 0; mt < 2; ++mt)
#pragma unroll
        for (int i = 0; i < 4; ++i) {
            const int row = mt * 16 + quad * 4 + i;
            sL[row * SL_STRIDE + CT0 * 16 + m15]       = acc[mt][0][i] + b0v;
            sL[row * SL_STRIDE + (CT0 + 1) * 16 + m15] = acc[mt][1][i] + b1v;
        }
    __syncthreads();

    // softmax: 8 threads/row, 16 cols each
    {
        const int row = t >> 3, s = t & 7;
        float* base = &sL[row * SL_STRIDE + s * 16];
        float v[16];
#pragma unroll
        for (int j = 0; j < 4; ++j) *(float4*)&v[j * 4] = *(const float4*)(base + j * 4);
        float m = -1e30f;
#pragma unroll
        for (int j = 0; j < 16; ++j) m = fmaxf(m, v[j]);
#pragma unroll
        for (int off = 1; off < 8; off <<= 1) m = fmaxf(m, __shfl_xor(m, off));
        float ssum = 0.f;
#pragma unroll
        for (int j = 0; j < 16; ++j) { v[j] = __expf(v[j] - m); ssum += v[j]; }
#pragma unroll
        for (int off = 1; off < 8; off <<= 1) ssum += __shfl_xor(ssum, off);
        const float inv = 1.0f / ssum;
#pragma unroll
        for (int j = 0; j < 16; ++j) v[j] *= inv;
#pragma unroll
        for (int j = 0; j < 4; ++j) *(float4*)(base + j * 4) = *(const float4*)&v[j * 4];
    }
    __syncthreads();

    // gather: 384 (row, j) entries
    float p = 0.f;
#pragma unroll
    for (int i = t; i < BM * VLn; i += 256) {
        const int gi  = r0 * VLn + i;
        const int row = i / VLn;
        const int idx = didx[gi];
        const int mk  = dmsk[gi];
        p += mk ? sL[row * SL_STRIDE + idx] : 0.f;
    }
#pragma unroll
    for (int off = 1; off < 64; off <<= 1) p += __shfl_xor(p, off);
    if (lane == 0) sRed[w] = p;
    __syncthreads();
    if (t == 0) part[blockIdx.x] = sRed[0] + sRed[1] + sRed[2] + sRed[3];
}

// Final reduce: 512 partials -> scalar
__global__ __launch_bounds__(256)
void reduce_k(const float* __restrict__ part, float* __restrict__ out) {
    __shared__ float s[4];
    const int t = threadIdx.x;
    float p = part[t] + part[t + 256];
#pragma unroll
    for (int off = 1; off < 64; off <<= 1) p += __shfl_xor(p, off);
    if ((t & 63) == 0) s[t >> 6] = p;
    __syncthreads();
    if (t == 0) out[0] = (s[0] + s[1] + s[2] + s[3]) * (1.0f / 65536.0f); // /(V*B)
}

extern "C" void kernel_launch(void* const* d_in, const int* in_sizes, int n_in,
                              void* d_out, int out_size, void* d_ws, size_t ws_size,
                              hipStream_t stream) {
    const float* emb  = (const float*)d_in[0];
    const float* W    = (const float*)d_in[1];
    const float* bias = (const float*)d_in[2];
    const int*   didx = (const int*)d_in[3];
    const int*   dmsk = (const int*)d_in[4];
    float* out = (float*)d_out;

    uint4* Wf   = (uint4*)d_ws;                        // 256 KB swizzled f16 W
    float* part = (float*)((char*)d_ws + 262144);      // 512 block partials

    conv_w<<<64, 256, 0, stream>>>(W, Wf);
    qloss_kernel<<<GRID, 256, 0, stream>>>(emb, Wf, bias, didx, dmsk, part);
    reduce_k<<<1, 256, 0, stream>>>(part, out);
}

// Round 7
// 114.586 us; speedup vs baseline: 1.4243x; 1.0082x over previous
//
#include <hip/hip_runtime.h>

// Problem constants
#define B_SIZE 16384
#define D_DIM  1024
#define T_DIM  128
#define VLn    12
#define BM     32             // rows per block
#define BK     64             // K per chunk
#define NCHUNK (D_DIM / BK)   // 16
#define GRID   (B_SIZE / BM)  // 512
#define SL_STRIDE 132

typedef _Float16 half8  __attribute__((ext_vector_type(8)));
typedef __fp16   fp16x2 __attribute__((ext_vector_type(2)));
typedef float    f32x4  __attribute__((ext_vector_type(4)));

union Pack16 { fp16x2 h[4]; uint4 u; };
union BReg   { uint4 u; half8 h; };

__device__ __forceinline__ uint4 pack8(float4 v0, float4 v1) {
    Pack16 un;
    un.h[0] = __builtin_amdgcn_cvt_pkrtz(v0.x, v0.y);
    un.h[1] = __builtin_amdgcn_cvt_pkrtz(v0.z, v0.w);
    un.h[2] = __builtin_amdgcn_cvt_pkrtz(v1.x, v1.y);
    un.h[3] = __builtin_amdgcn_cvt_pkrtz(v1.z, v1.w);
    return un.u;
}

// W fp32 [128][1024] -> f16, swizzled into MFMA B-fragment order:
// unit j (16 B = 8 f16): kc=j>>10, g=(j&1023)>>6 (g = ks*8+CT), lane=j&63;
// holds W[n = CT*16 + (lane&15)][k = kc*64 + ks*32 + (lane>>4)*8 .. +8].
__global__ __launch_bounds__(256)
void conv_w(const float* __restrict__ W, uint4* __restrict__ Wf) {
    const int j    = blockIdx.x * 256 + threadIdx.x;   // 0..16383
    const int kc   = j >> 10;
    const int r    = j & 1023;
    const int g    = r >> 6;
    const int lane = r & 63;
    const int ks = g >> 3, CT = g & 7;
    const int n = CT * 16 + (lane & 15);
    const int k = kc * 64 + ks * 32 + ((lane >> 4) << 3);
    const float* src = W + (size_t)n * D_DIM + k;
    const float4 v0 = *(const float4*)src;
    const float4 v1 = *(const float4*)(src + 4);
    Wf[j] = pack8(v0, v1);
}

// 512 blocks x 256 threads (4 waves) = exactly 2 blocks/CU.
// Block = 32 rows x 128 cols x full K. Wave w owns cols [w*32, w*32+32).
// A: double-buffered LDS, 2-DEEP register prefetch (ds_write consumes data
// loaded a full iteration earlier -> no vmcnt stall on the barrier path).
// B: direct global frag loads from pre-swizzled Wf, 2-deep in registers.
__global__ __launch_bounds__(256, 2)
void qloss_kernel(const float* __restrict__ emb,
                  const uint4* __restrict__ Wf,
                  const float* __restrict__ bias,
                  const int*   __restrict__ didx,
                  const int*   __restrict__ dmsk,
                  float*       __restrict__ out)
{
    __shared__ __align__(16) unsigned char smem[16928];
    // staging: sA0 @0 (4 KB), sA1 @4096. epilogue alias: sL [32][132] f32 + sRed
    float* sL   = (float*)smem;
    float* sRed = (float*)(smem + 16896);

    const int t    = threadIdx.x;
    const int w    = t >> 6;
    const int lane = t & 63;
    const int m15  = lane & 15;
    const int quad = lane >> 4;
    const int r0   = blockIdx.x * BM;

    // A staging map (verified): thread t stages unit t each chunk.
    // unit t: g=t>>6 (mt=g>>1, ks=g&1), sl=t&63;
    // row = mt*16 + (sl&15), k-offset = ks*32 + (sl>>4)*8.
    const int sg   = t >> 6, sl = t & 63;
    const int srow = (sg >> 1) * 16 + (sl & 15);
    const int skk  = (sg & 1) * 32 + ((sl >> 4) << 3);
    const float* aBase = emb + (size_t)(r0 + srow) * D_DIM + skk;

    // B-frag base: wave w, frag (ks, j): Wf[kc*1024 + (ks*8 + 2w+j)*64 + lane]
    const uint4* wBase = Wf + (size_t)(2 * w) * 64 + lane;

    f32x4 acc[2][2];
#pragma unroll
    for (int mt = 0; mt < 2; ++mt)
#pragma unroll
        for (int ct = 0; ct < 2; ++ct) acc[mt][ct] = (f32x4){0.f, 0.f, 0.f, 0.f};

    // ---- prologue: A(0) -> LDS buf0; A(1) -> regs; B(0), B(1) -> regs ----
    BReg bcur[4], bnx1[4], bnx2[4];
    float4 an0, an1, af0, af1;
    {
        const float4 v0 = *(const float4*)(aBase);
        const float4 v1 = *(const float4*)(aBase + 4);
        an0 = *(const float4*)(aBase + 64);
        an1 = *(const float4*)(aBase + 68);
#pragma unroll
        for (int ks = 0; ks < 2; ++ks)
#pragma unroll
            for (int j = 0; j < 2; ++j) {
                bcur[ks * 2 + j].u = wBase[(size_t)(ks * 8 + j) * 64];
                bnx1[ks * 2 + j].u = wBase[(size_t)1 * 1024 + (ks * 8 + j) * 64];
            }
        *(uint4*)(smem + t * 16) = pack8(v0, v1);
    }
    __syncthreads();

#pragma unroll
    for (int kc = 0; kc < NCHUNK; ++kc) {
        unsigned char* sAc = smem + (kc & 1) * 4096;
        unsigned char* sAn = smem + ((kc & 1) ^ 1) * 4096;

        // issue loads for chunk kc+2 (arrive during the NEXT iteration)
        if (kc + 2 < NCHUNK) {
            af0 = *(const float4*)(aBase + (kc + 2) * 64);
            af1 = *(const float4*)(aBase + (kc + 2) * 64 + 4);
#pragma unroll
            for (int ks = 0; ks < 2; ++ks)
#pragma unroll
                for (int j = 0; j < 2; ++j)
                    bnx2[ks * 2 + j].u =
                        wBase[(size_t)(kc + 2) * 1024 + (ks * 8 + j) * 64];
        }

        // compute chunk kc: A frags from LDS, B frags from registers
#pragma unroll
        for (int ks = 0; ks < 2; ++ks) {
            const half8 a0 = *(const half8*)(sAc + ((0 * 2 + ks) * 64 + lane) * 16);
            const half8 a1 = *(const half8*)(sAc + ((1 * 2 + ks) * 64 + lane) * 16);
            acc[0][0] = __builtin_amdgcn_mfma_f32_16x16x32_f16(a0, bcur[ks * 2 + 0].h, acc[0][0], 0, 0, 0);
            acc[0][1] = __builtin_amdgcn_mfma_f32_16x16x32_f16(a0, bcur[ks * 2 + 1].h, acc[0][1], 0, 0, 0);
            acc[1][0] = __builtin_amdgcn_mfma_f32_16x16x32_f16(a1, bcur[ks * 2 + 0].h, acc[1][0], 0, 0, 0);
            acc[1][1] = __builtin_amdgcn_mfma_f32_16x16x32_f16(a1, bcur[ks * 2 + 1].h, acc[1][1], 0, 0, 0);
        }

        // stage A(kc+1) from regs loaded LAST iteration (vmcnt long satisfied)
        if (kc + 1 < NCHUNK)
            *(uint4*)(sAn + t * 16) = pack8(an0, an1);
        __syncthreads();

        // rotate pipelines
        an0 = af0; an1 = af1;
#pragma unroll
        for (int q = 0; q < 4; ++q) { bcur[q] = bnx1[q]; bnx1[q] = bnx2[q]; }
    }

    // ---- epilogue: logits -> sL ----
    const int CT0 = w * 2;
    const float b0v = bias[CT0 * 16 + m15];
    const float b1v = bias[(CT0 + 1) * 16 + m15];
#pragma unroll
    for (int mt = 0; mt < 2; ++mt)
#pragma unroll
        for (int i = 0; i < 4; ++i) {
            const int row = mt * 16 + quad * 4 + i;
            sL[row * SL_STRIDE + CT0 * 16 + m15]       = acc[mt][0][i] + b0v;
            sL[row * SL_STRIDE + (CT0 + 1) * 16 + m15] = acc[mt][1][i] + b1v;
        }
    __syncthreads();

    // softmax: 8 threads/row, 16 cols each
    {
        const int row = t >> 3, s = t & 7;
        float* base = &sL[row * SL_STRIDE + s * 16];
        float v[16];
#pragma unroll
        for (int j = 0; j < 4; ++j) *(float4*)&v[j * 4] = *(const float4*)(base + j * 4);
        float m = -1e30f;
#pragma unroll
        for (int j = 0; j < 16; ++j) m = fmaxf(m, v[j]);
#pragma unroll
        for (int off = 1; off < 8; off <<= 1) m = fmaxf(m, __shfl_xor(m, off));
        float ssum = 0.f;
#pragma unroll
        for (int j = 0; j < 16; ++j) { v[j] = __expf(v[j] - m); ssum += v[j]; }
#pragma unroll
        for (int off = 1; off < 8; off <<= 1) ssum += __shfl_xor(ssum, off);
        const float inv = 1.0f / ssum;
#pragma unroll
        for (int j = 0; j < 16; ++j) v[j] *= inv;
#pragma unroll
        for (int j = 0; j < 4; ++j) *(float4*)(base + j * 4) = *(const float4*)&v[j * 4];
    }
    __syncthreads();

    // gather: 384 (row, j) entries; block partial -> one atomicAdd
    float p = 0.f;
#pragma unroll
    for (int i = t; i < BM * VLn; i += 256) {
        const int gi  = r0 * VLn + i;
        const int row = i / VLn;
        const int idx = didx[gi];
        const int mk  = dmsk[gi];
        p += mk ? sL[row * SL_STRIDE + idx] : 0.f;
    }
#pragma unroll
    for (int off = 1; off < 64; off <<= 1) p += __shfl_xor(p, off);
    if (lane == 0) sRed[w] = p;
    __syncthreads();
    if (t == 0)
        atomicAdd(out, (sRed[0] + sRed[1] + sRed[2] + sRed[3]) * (1.0f / 65536.0f));
}

extern "C" void kernel_launch(void* const* d_in, const int* in_sizes, int n_in,
                              void* d_out, int out_size, void* d_ws, size_t ws_size,
                              hipStream_t stream) {
    const float* emb  = (const float*)d_in[0];
    const float* W    = (const float*)d_in[1];
    const float* bias = (const float*)d_in[2];
    const int*   didx = (const int*)d_in[3];
    const int*   dmsk = (const int*)d_in[4];
    float* out = (float*)d_out;

    uint4* Wf = (uint4*)d_ws;   // 256 KB swizzled f16 W

    hipMemsetAsync(out, 0, sizeof(float), stream);
    conv_w<<<64, 256, 0, stream>>>(W, Wf);
    qloss_kernel<<<GRID, 256, 0, stream>>>(emb, Wf, bias, didx, dmsk, out);
}